// Round 8
// baseline (538.031 us; speedup 1.0000x reference)
//
#include <hip/hip_runtime.h>
#include <hip/hip_bf16.h>
#include <hip/hip_fp16.h>

typedef float f4 __attribute__((ext_vector_type(4)));
typedef unsigned int u32x2 __attribute__((ext_vector_type(2)));
typedef _Float16 h8 __attribute__((ext_vector_type(8)));

__device__ __forceinline__ __half2 bits2h2(unsigned u) {
    union { unsigned u; __half2 h; } c; c.u = u; return c.h;
}
__device__ __forceinline__ unsigned h22bits(__half2 h) {
    union { unsigned u; __half2 h; } c; c.h = h; return c.u;
}

#define N_NODES   100000
#define EMBED     128
#define N_USERS_T 50000
#define N_ITEMS   50000

#define BSH   8                 // bucket = dst >> 8
#define NB    391               // ceil(100000 / 256)
#define NBLK  256               // partition blocks

// ---------- K1: per-block bucket histogram ----------
__global__ __launch_bounds__(256) void part_hist(const int* __restrict__ dst,
                                                 int* __restrict__ blkhist,
                                                 int n, int epb) {
    __shared__ int h[NB];
    for (int j = threadIdx.x; j < NB; j += 256) h[j] = 0;
    __syncthreads();
    int b = blockIdx.x, s = b * epb, e = min(n, s + epb);
    for (int i = s + (int)threadIdx.x; i < e; i += 256)
        atomicAdd(&h[dst[i] >> BSH], 1);
    __syncthreads();
    for (int j = threadIdx.x; j < NB; j += 256) blkhist[b * NB + j] = h[j];
}

// ---------- K2a: per-bucket exclusive scan across blocks ----------
__global__ __launch_bounds__(256) void part_cursors(const int* __restrict__ blkhist,
                                                    int* __restrict__ cursors,
                                                    int* __restrict__ total) {
    int bu = blockIdx.x, t = threadIdx.x;
    int v = blkhist[t * NB + bu];
    int lane = t & 63, wid = t >> 6;
    int x = v;
    #pragma unroll
    for (int off = 1; off < 64; off <<= 1) {
        int y = __shfl_up(x, off, 64);
        if (lane >= off) x += y;
    }
    __shared__ int ws4[4];
    if (lane == 63) ws4[wid] = x;
    __syncthreads();
    int add = 0;
    for (int j = 0; j < wid; ++j) add += ws4[j];
    cursors[t * NB + bu] = add + x - v;      // exclusive over blocks
    if (t == 255) total[bu] = add + x;       // bucket size
}

// ---------- K2b: bucket base (serial tiny scan) ----------
__global__ void bucket_base_scan(const int* __restrict__ total,
                                 int* __restrict__ base) {
    if (threadIdx.x == 0) {
        int s = 0;
        for (int j = 0; j < NB; ++j) { base[j] = s; s += total[j]; }
        base[NB] = s;
    }
}

// ---------- K3: partition into buckets (block-private slices) ----------
// part entry: .x = src | (dst_low8 << 17), .y = w bits
__global__ __launch_bounds__(256) void part_scatter(const int* __restrict__ src,
                                                    const int* __restrict__ dst,
                                                    const float* __restrict__ w,
                                                    const int* __restrict__ cursors,
                                                    const int* __restrict__ base,
                                                    int2* __restrict__ part,
                                                    int n, int epb) {
    __shared__ int cur[NB];
    int b = blockIdx.x;
    for (int j = threadIdx.x; j < NB; j += 256)
        cur[j] = base[j] + cursors[b * NB + j];
    __syncthreads();
    int s = b * epb, e = min(n, s + epb);
    for (int i = s + (int)threadIdx.x; i < e; i += 256) {
        int d = dst[i];
        int bu = d >> BSH;
        int p = atomicAdd(&cur[bu], 1);
        int2 pe;
        pe.x = src[i] | ((d & 255) << 17);
        pe.y = __float_as_int(w[i]);
        part[p] = pe;
    }
}

// ---------- K4: per-bucket fine CSR; emits compressed edge u32 -------------
// edge u32 = src (17b) | wq (15b fixed-point w*32768)
__global__ __launch_bounds__(512) void bucket_csr(const int2* __restrict__ part,
                                                  const int* __restrict__ base,
                                                  int* __restrict__ off_end,
                                                  unsigned* __restrict__ ep,
                                                  int n_nodes) {
    __shared__ int cnt[256], cur2[256], ws4[4];
    int bu = blockIdx.x, t = threadIdx.x;
    int b0 = base[bu], b1 = base[bu + 1];
    if (t < 256) cnt[t] = 0;
    __syncthreads();
    for (int i = b0 + t; i < b1; i += 512)
        atomicAdd(&cnt[(part[i].x >> 17) & 255], 1);
    __syncthreads();
    int lane = t & 63, wid = t >> 6;
    int v = 0, x = 0;
    if (t < 256) {
        v = cnt[t]; x = v;
        #pragma unroll
        for (int off = 1; off < 64; off <<= 1) {
            int y = __shfl_up(x, off, 64);
            if (lane >= off) x += y;
        }
        if (lane == 63) ws4[wid] = x;
    }
    __syncthreads();
    if (t < 256) {
        int add = 0;
        for (int j = 0; j < wid; ++j) add += ws4[j];
        int incl = add + x;
        int node = (bu << BSH) + t;
        if (node < n_nodes) off_end[node] = b0 + incl;
        cur2[t] = b0 + incl - v;             // exclusive start
    }
    __syncthreads();
    for (int i = b0 + t; i < b1; i += 512) {
        int2 pe = part[i];
        int dloc = (pe.x >> 17) & 255;
        int p = atomicAdd(&cur2[dloc], 1);
        float wf = __int_as_float(pe.y);
        int wq = (int)(wf * 32768.f + 0.5f);
        wq = min(max(wq, 0), 32767);
        ep[p] = (unsigned)(pe.x & 0x1FFFF) | ((unsigned)wq << 17);
    }
}

// ---------- fp32 -> fp16 row conversion ----------
__global__ __launch_bounds__(256) void f2h_kernel(const float* __restrict__ in,
                                                  __half* __restrict__ out, int n4) {
    int i = blockIdx.x * 256 + threadIdx.x;
    if (i < n4) {
        f4 v = ((const f4*)in)[i];
        u32x2 o;
        o.x = h22bits(__floats2half2_rn(v.x, v.y));
        o.y = h22bits(__floats2half2_rn(v.z, v.w));
        ((u32x2*)out)[i] = o;
    }
}

// ---------- propagation layer: fp16 gather -> fp16 rep ----------
// NOTE: rep_out stores are CACHED (no nontemporal) — the next layer re-reads
// this buffer 819 MB/layer; nt hint was evicting it from L2/L3 (round-7 PMC:
// 347 MB FETCH vs 25.6 MB working set).
__global__ __launch_bounds__(256) void layer_kernel(
        const __half* __restrict__ rep_in, __half* __restrict__ rep_out,
        const int* __restrict__ off_end, const unsigned* __restrict__ ep,
        int n_nodes) {
    int node = blockIdx.x * 4 + (threadIdx.x >> 6);
    if (node >= n_nodes) return;
    int lane = threadIdx.x & 63;
    int half = lane >> 5;
    int l32  = lane & 31;
    int beg = (node == 0) ? 0 : off_end[node - 1];
    int end = off_end[node];
    f4 s = {0.f, 0.f, 0.f, 0.f};
    const u32x2* rp = (const u32x2*)rep_in;
    for (int chunk = beg; chunk < end; chunk += 64) {
        int idx = chunk + lane;
        unsigned ev = (idx < end) ? ep[idx] : 0u;
        int m = end - chunk; if (m > 64) m = 64;
        #pragma unroll 8
        for (int j = 0; j < m; j += 2) {
            unsigned v = __shfl(ev, j + half);   // j+half==m edge: lane m holds 0 -> harmless
            int   sn = v & 0x1FFFF;
            float wt = (float)(v >> 17) * (1.f / 32768.f);
            u32x2 rv = rp[(size_t)sn * 32 + l32];
            float2 f0 = __half22float2(bits2h2(rv.x));
            float2 f1 = __half22float2(bits2h2(rv.y));
            s.x = fmaf(wt, f0.x, s.x);
            s.y = fmaf(wt, f0.y, s.y);
            s.z = fmaf(wt, f1.x, s.z);
            s.w = fmaf(wt, f1.y, s.w);
        }
    }
    s.x += __shfl_xor(s.x, 32);
    s.y += __shfl_xor(s.y, 32);
    s.z += __shfl_xor(s.z, 32);
    s.w += __shfl_xor(s.w, 32);
    if (half == 0) {
        u32x2 ov;
        ov.x = h22bits(__floats2half2_rn(s.x, s.y));
        ov.y = h22bits(__floats2half2_rn(s.z, s.w));
        ((u32x2*)rep_out)[(size_t)node * 32 + l32] = ov;
    }
}

// ---------- final user rows: 0.25*(emb + r1 + r2 + r3), fp16 out ----------
__global__ __launch_bounds__(256) void gather_users(const int* __restrict__ users,
                                                    const float* __restrict__ emb,
                                                    const __half* __restrict__ r1,
                                                    const __half* __restrict__ r2,
                                                    const __half* __restrict__ r3,
                                                    _Float16* __restrict__ ur, int nu) {
    int idx = blockIdx.x * 256 + threadIdx.x;
    int u = idx >> 5;
    int q = idx & 31;
    if (u >= nu) return;
    size_t row = (size_t)users[u];
    f4 e = *(const f4*)(emb + row * EMBED + q * 4);
    size_t p = row * 32 + q;
    u32x2 a = ((const u32x2*)r1)[p];
    u32x2 b = ((const u32x2*)r2)[p];
    u32x2 c = ((const u32x2*)r3)[p];
    float2 a0 = __half22float2(bits2h2(a.x)), a1 = __half22float2(bits2h2(a.y));
    float2 b0 = __half22float2(bits2h2(b.x)), b1 = __half22float2(bits2h2(b.y));
    float2 c0 = __half22float2(bits2h2(c.x)), c1 = __half22float2(bits2h2(c.y));
    float v0 = (e.x + a0.x + b0.x + c0.x) * 0.25f;
    float v1 = (e.y + a0.y + b0.y + c0.y) * 0.25f;
    float v2 = (e.z + a1.x + b1.x + c1.x) * 0.25f;
    float v3 = (e.w + a1.y + b1.y + c1.y) * 0.25f;
    u32x2 o;
    o.x = h22bits(__floats2half2_rn(v0, v1));
    o.y = h22bits(__floats2half2_rn(v2, v3));
    *(u32x2*)(ur + (size_t)u * EMBED + q * 4) = o;
}

// ---------- final item rows: 0.25*(emb + r1 + r2 + r3), fp16 out ----------
__global__ __launch_bounds__(256) void copy_items(const float* __restrict__ emb,
                                                  const __half* __restrict__ r1,
                                                  const __half* __restrict__ r2,
                                                  const __half* __restrict__ r3,
                                                  _Float16* __restrict__ ir, int ni) {
    int idx = blockIdx.x * 256 + threadIdx.x;
    int i = idx >> 5;
    int q = idx & 31;
    if (i >= ni) return;
    size_t row = (size_t)(N_USERS_T + i);
    f4 e = *(const f4*)(emb + row * EMBED + q * 4);
    size_t p = row * 32 + q;
    u32x2 a = ((const u32x2*)r1)[p];
    u32x2 b = ((const u32x2*)r2)[p];
    u32x2 c = ((const u32x2*)r3)[p];
    float2 a0 = __half22float2(bits2h2(a.x)), a1 = __half22float2(bits2h2(a.y));
    float2 b0 = __half22float2(bits2h2(b.x)), b1 = __half22float2(bits2h2(b.y));
    float2 c0 = __half22float2(bits2h2(c.x)), c1 = __half22float2(bits2h2(c.y));
    float v0 = (e.x + a0.x + b0.x + c0.x) * 0.25f;
    float v1 = (e.y + a0.y + b0.y + c0.y) * 0.25f;
    float v2 = (e.z + a1.x + b1.x + c1.x) * 0.25f;
    float v3 = (e.w + a1.y + b1.y + c1.y) * 0.25f;
    u32x2 o;
    o.x = h22bits(__floats2half2_rn(v0, v1));
    o.y = h22bits(__floats2half2_rn(v2, v3));
    *(u32x2*)(ir + (size_t)i * EMBED + q * 4) = o;
}

// ---------- MFMA fp16 GEMM: C[nu x nI] = U[nu x 128] * I[nI x 128]^T -------
__global__ __launch_bounds__(256) void gemm_mfma(const _Float16* __restrict__ U,
                                                 const _Float16* __restrict__ I,
                                                 float* __restrict__ C,
                                                 int nu, int nI) {
    int wave = threadIdx.x >> 6;
    int lane = threadIdx.x & 63;
    int i0 = (blockIdx.x * 4 + wave) * 64;
    int u0 = blockIdx.y * 64;
    if (i0 >= nI) return;
    int l16 = lane & 15;
    int kg  = lane >> 4;
    f4 acc[4][4] = {};
    bool inb[4];
    #pragma unroll
    for (int nt = 0; nt < 4; ++nt) inb[nt] = (i0 + nt * 16 + l16) < nI;
    #pragma unroll
    for (int kk = 0; kk < 4; ++kk) {
        const int ko = kk * 32 + kg * 8;
        h8 a[4], b[4];
        #pragma unroll
        for (int mt = 0; mt < 4; ++mt)
            a[mt] = *(const h8*)(U + (size_t)(u0 + mt * 16 + l16) * EMBED + ko);
        #pragma unroll
        for (int nt = 0; nt < 4; ++nt) {
            h8 z = {};
            b[nt] = inb[nt] ? *(const h8*)(I + (size_t)(i0 + nt * 16 + l16) * EMBED + ko) : z;
        }
        #pragma unroll
        for (int mt = 0; mt < 4; ++mt)
            #pragma unroll
            for (int nt = 0; nt < 4; ++nt)
                acc[mt][nt] = __builtin_amdgcn_mfma_f32_16x16x32_f16(a[mt], b[nt], acc[mt][nt], 0, 0, 0);
    }
    #pragma unroll
    for (int mt = 0; mt < 4; ++mt) {
        #pragma unroll
        for (int r = 0; r < 4; ++r) {
            int row = u0 + mt * 16 + kg * 4 + r;
            if (row >= nu) continue;
            float* Cr = C + (size_t)row * nI;
            #pragma unroll
            for (int nt = 0; nt < 4; ++nt) {
                int col = i0 + nt * 16 + l16;
                if (col < nI)
                    __builtin_nontemporal_store(acc[mt][nt][r], Cr + col);
            }
        }
    }
}

extern "C" void kernel_launch(void* const* d_in, const int* in_sizes, int n_in,
                              void* d_out, int out_size, void* d_ws, size_t ws_size,
                              hipStream_t stream) {
    const float* emb   = (const float*)d_in[0];
    const float* ew    = (const float*)d_in[1];
    const int*   esrc  = (const int*)d_in[2];
    const int*   edst  = (const int*)d_in[3];
    const int*   users = (const int*)d_in[4];
    const int n_edges = in_sizes[1];
    const int n_nodes = in_sizes[0] / EMBED;
    const int nu      = in_sizes[4];

    // ---- workspace layout (~27 MB) ----
    char* ws = (char*)d_ws;
    int*      off_end = (int*)ws;                           // 400128 B
    int*      blkhist = (int*)(ws + 400128);                // 400512 B
    int*      cursors = (int*)(ws + 800640);                // 400512 B
    int*      total   = (int*)(ws + 1201152);               // 1664 B
    int*      bbase   = (int*)(ws + 1202816);               // 1664 B
    unsigned* epc     = (unsigned*)(ws + 1204480);          // 12.8 MB
    _Float16* ur      = (_Float16*)(ws + 1204480 + 12800000);           // 256 KB
    _Float16* ir      = (_Float16*)(ws + 1204480 + 12800000 + 262144);  // 12.8 MB

    // ---- d_out doubles as scratch until the final GEMM overwrites it ----
    __half* emb_h   = (__half*)d_out;                       // 25.6 MB
    __half* rep1_h  = emb_h + (size_t)12800000;             // 25.6 MB
    __half* rep2_h  = emb_h + (size_t)2 * 12800000;         // 25.6 MB
    __half* rep3_h  = emb_h + (size_t)3 * 12800000;         // 25.6 MB
    int2*   part_ep = (int2*)(emb_h + (size_t)4 * 12800000);// 25.6 MB (byte 102.4M)
    float*  out     = (float*)d_out;

    const int epb = (n_edges + NBLK - 1) / NBLK;

    // 1) two-level CSR build (compressed edge payload)
    part_hist   <<<NBLK, 256, 0, stream>>>(edst, blkhist, n_edges, epb);
    part_cursors<<<NB,   256, 0, stream>>>(blkhist, cursors, total);
    bucket_base_scan<<<1, 64, 0, stream>>>(total, bbase);
    part_scatter<<<NBLK, 256, 0, stream>>>(esrc, edst, ew, cursors, bbase,
                                           part_ep, n_edges, epb);
    bucket_csr  <<<NB,   512, 0, stream>>>(part_ep, bbase, off_end, epc, n_nodes);

    // 2) fp16 copy of embedding for layer-1 gathers
    int n4 = n_nodes * EMBED / 4;
    f2h_kernel<<<(n4 + 255) / 256, 256, 0, stream>>>(emb, emb_h, n4);

    // 3) three propagation layers (fp16 gather, fp32 math, fp16 rep out)
    const int lgrid = (n_nodes + 3) / 4;
    layer_kernel<<<lgrid, 256, 0, stream>>>(emb_h,  rep1_h, off_end, epc, n_nodes);
    layer_kernel<<<lgrid, 256, 0, stream>>>(rep1_h, rep2_h, off_end, epc, n_nodes);
    layer_kernel<<<lgrid, 256, 0, stream>>>(rep2_h, rep3_h, off_end, epc, n_nodes);

    // 4) final rows: 0.25*(emb + r1 + r2 + r3) -> fp16 ur / ir
    gather_users<<<(nu * 32 + 255) / 256, 256, 0, stream>>>(users, emb, rep1_h, rep2_h, rep3_h, ur, nu);
    copy_items<<<(N_ITEMS * 32 + 255) / 256, 256, 0, stream>>>(emb, rep1_h, rep2_h, rep3_h, ir, N_ITEMS);

    // 5) scores = ur @ ir^T via fp16 MFMA (fp32 accumulate)
    dim3 ggrid((N_ITEMS + 255) / 256, (nu + 63) / 64);
    gemm_mfma<<<ggrid, 256, 0, stream>>>(ur, ir, out, nu, N_ITEMS);
}

// Round 10
// 501.248 us; speedup vs baseline: 1.0734x; 1.0734x over previous
//
#include <hip/hip_runtime.h>
#include <hip/hip_bf16.h>
#include <hip/hip_fp16.h>

typedef float f4 __attribute__((ext_vector_type(4)));
typedef unsigned int u32x2 __attribute__((ext_vector_type(2)));
typedef _Float16 h8 __attribute__((ext_vector_type(8)));

__device__ __forceinline__ __half2 bits2h2(unsigned u) {
    union { unsigned u; __half2 h; } c; c.u = u; return c.h;
}
__device__ __forceinline__ unsigned h22bits(__half2 h) {
    union { unsigned u; __half2 h; } c; c.h = h; return c.u;
}

#define N_NODES   100000
#define EMBED     128
#define N_USERS_T 50000
#define N_ITEMS   50000

#define BSH   8                 // bucket = dst >> 8
#define NB    391               // ceil(100000 / 256)
#define NBLK  256               // partition blocks

// ---------- K1: per-block bucket histogram ----------
__global__ __launch_bounds__(256) void part_hist(const int* __restrict__ dst,
                                                 int* __restrict__ blkhist,
                                                 int n, int epb) {
    __shared__ int h[NB];
    for (int j = threadIdx.x; j < NB; j += 256) h[j] = 0;
    __syncthreads();
    int b = blockIdx.x, s = b * epb, e = min(n, s + epb);
    for (int i = s + (int)threadIdx.x; i < e; i += 256)
        atomicAdd(&h[dst[i] >> BSH], 1);
    __syncthreads();
    for (int j = threadIdx.x; j < NB; j += 256) blkhist[b * NB + j] = h[j];
}

// ---------- K2a: per-bucket exclusive scan across blocks ----------
__global__ __launch_bounds__(256) void part_cursors(const int* __restrict__ blkhist,
                                                    int* __restrict__ cursors,
                                                    int* __restrict__ total) {
    int bu = blockIdx.x, t = threadIdx.x;
    int v = blkhist[t * NB + bu];
    int lane = t & 63, wid = t >> 6;
    int x = v;
    #pragma unroll
    for (int off = 1; off < 64; off <<= 1) {
        int y = __shfl_up(x, off, 64);
        if (lane >= off) x += y;
    }
    __shared__ int ws4[4];
    if (lane == 63) ws4[wid] = x;
    __syncthreads();
    int add = 0;
    for (int j = 0; j < wid; ++j) add += ws4[j];
    cursors[t * NB + bu] = add + x - v;      // exclusive over blocks
    if (t == 255) total[bu] = add + x;       // bucket size
}

// ---------- K2b: bucket base (serial tiny scan) ----------
__global__ void bucket_base_scan(const int* __restrict__ total,
                                 int* __restrict__ base) {
    if (threadIdx.x == 0) {
        int s = 0;
        for (int j = 0; j < NB; ++j) { base[j] = s; s += total[j]; }
        base[NB] = s;
    }
}

// ---------- K3: partition into buckets (block-private slices) ----------
// part entry: .x = src | (dst_low8 << 17), .y = w bits
__global__ __launch_bounds__(256) void part_scatter(const int* __restrict__ src,
                                                    const int* __restrict__ dst,
                                                    const float* __restrict__ w,
                                                    const int* __restrict__ cursors,
                                                    const int* __restrict__ base,
                                                    int2* __restrict__ part,
                                                    int n, int epb) {
    __shared__ int cur[NB];
    int b = blockIdx.x;
    for (int j = threadIdx.x; j < NB; j += 256)
        cur[j] = base[j] + cursors[b * NB + j];
    __syncthreads();
    int s = b * epb, e = min(n, s + epb);
    for (int i = s + (int)threadIdx.x; i < e; i += 256) {
        int d = dst[i];
        int bu = d >> BSH;
        int p = atomicAdd(&cur[bu], 1);
        int2 pe;
        pe.x = src[i] | ((d & 255) << 17);
        pe.y = __float_as_int(w[i]);
        part[p] = pe;
    }
}

// ---------- K4: per-bucket fine CSR; emits compressed edge u32 -------------
// edge u32 = src (17b) | wq (15b fixed-point w*32768)
__global__ __launch_bounds__(512) void bucket_csr(const int2* __restrict__ part,
                                                  const int* __restrict__ base,
                                                  int* __restrict__ off_end,
                                                  unsigned* __restrict__ ep,
                                                  int n_nodes) {
    __shared__ int cnt[256], cur2[256], ws4[4];
    int bu = blockIdx.x, t = threadIdx.x;
    int b0 = base[bu], b1 = base[bu + 1];
    if (t < 256) cnt[t] = 0;
    __syncthreads();
    for (int i = b0 + t; i < b1; i += 512)
        atomicAdd(&cnt[(part[i].x >> 17) & 255], 1);
    __syncthreads();
    int lane = t & 63, wid = t >> 6;
    int v = 0, x = 0;
    if (t < 256) {
        v = cnt[t]; x = v;
        #pragma unroll
        for (int off = 1; off < 64; off <<= 1) {
            int y = __shfl_up(x, off, 64);
            if (lane >= off) x += y;
        }
        if (lane == 63) ws4[wid] = x;
    }
    __syncthreads();
    if (t < 256) {
        int add = 0;
        for (int j = 0; j < wid; ++j) add += ws4[j];
        int incl = add + x;
        int node = (bu << BSH) + t;
        if (node < n_nodes) off_end[node] = b0 + incl;
        cur2[t] = b0 + incl - v;             // exclusive start
    }
    __syncthreads();
    for (int i = b0 + t; i < b1; i += 512) {
        int2 pe = part[i];
        int dloc = (pe.x >> 17) & 255;
        int p = atomicAdd(&cur2[dloc], 1);
        float wf = __int_as_float(pe.y);
        int wq = (int)(wf * 32768.f + 0.5f);
        wq = min(max(wq, 0), 32767);
        ep[p] = (unsigned)(pe.x & 0x1FFFF) | ((unsigned)wq << 17);
    }
}

// ---------- fp32 -> fp16 row conversion ----------
__global__ __launch_bounds__(256) void f2h_kernel(const float* __restrict__ in,
                                                  __half* __restrict__ out, int n4) {
    int i = blockIdx.x * 256 + threadIdx.x;
    if (i < n4) {
        f4 v = ((const f4*)in)[i];
        u32x2 o;
        o.x = h22bits(__floats2half2_rn(v.x, v.y));
        o.y = h22bits(__floats2half2_rn(v.z, v.w));
        ((u32x2*)out)[i] = o;
    }
}

// ---------- propagation layer: fp16 gather -> fp16 rep ----------
// Hand-batched 8-deep gather pipeline with UNIFORM control flow: step count
// np=(m+1)>>1 is identical for all 64 lanes (round-9 lesson: per-half trip
// counts made wave-wide __shfl sit in divergent control flow -> wrong sums).
// The only index overrun (j==m, odd m, half=1) reads lane m, which holds
// ev=0 -> weight-0 gather of node 0, harmless (round-7 trick).
__global__ __launch_bounds__(256) void layer_kernel(
        const __half* __restrict__ rep_in, __half* __restrict__ rep_out,
        const int* __restrict__ off_end, const unsigned* __restrict__ ep,
        int n_nodes) {
    int node = blockIdx.x * 4 + (threadIdx.x >> 6);
    if (node >= n_nodes) return;
    int lane = threadIdx.x & 63;
    int half = lane >> 5;
    int l32  = lane & 31;
    int beg = (node == 0) ? 0 : off_end[node - 1];
    int end = off_end[node];
    f4 s = {0.f, 0.f, 0.f, 0.f};
    const u32x2* rp = (const u32x2*)rep_in;

    auto acc1 = [&](unsigned v, u32x2 rv) {
        float wt = (float)(v >> 17) * (1.f / 32768.f);
        float2 f0 = __half22float2(bits2h2(rv.x));
        float2 f1 = __half22float2(bits2h2(rv.y));
        s.x = fmaf(wt, f0.x, s.x);
        s.y = fmaf(wt, f0.y, s.y);
        s.z = fmaf(wt, f1.x, s.z);
        s.w = fmaf(wt, f1.y, s.w);
    };

    for (int chunk = beg; chunk < end; chunk += 64) {
        int idx = chunk + lane;
        unsigned ev = (idx < end) ? ep[idx] : 0u;
        int m = end - chunk; if (m > 64) m = 64;
        int np = (m + 1) >> 1;            // pair steps: UNIFORM across wave
        int p = 0;
        for (; p + 8 <= np; p += 8) {
            int jb = p * 2 + half;
            unsigned v0 = __shfl(ev, jb +  0);
            unsigned v1 = __shfl(ev, jb +  2);
            unsigned v2 = __shfl(ev, jb +  4);
            unsigned v3 = __shfl(ev, jb +  6);
            unsigned v4 = __shfl(ev, jb +  8);
            unsigned v5 = __shfl(ev, jb + 10);
            unsigned v6 = __shfl(ev, jb + 12);
            unsigned v7 = __shfl(ev, jb + 14);
            u32x2 r0 = rp[(size_t)(v0 & 0x1FFFF) * 32 + l32];
            u32x2 r1 = rp[(size_t)(v1 & 0x1FFFF) * 32 + l32];
            u32x2 r2 = rp[(size_t)(v2 & 0x1FFFF) * 32 + l32];
            u32x2 r3 = rp[(size_t)(v3 & 0x1FFFF) * 32 + l32];
            u32x2 r4 = rp[(size_t)(v4 & 0x1FFFF) * 32 + l32];
            u32x2 r5 = rp[(size_t)(v5 & 0x1FFFF) * 32 + l32];
            u32x2 r6 = rp[(size_t)(v6 & 0x1FFFF) * 32 + l32];
            u32x2 r7 = rp[(size_t)(v7 & 0x1FFFF) * 32 + l32];
            acc1(v0, r0); acc1(v1, r1); acc1(v2, r2); acc1(v3, r3);
            acc1(v4, r4); acc1(v5, r5); acc1(v6, r6); acc1(v7, r7);
        }
        for (; p < np; ++p) {
            unsigned v = __shfl(ev, p * 2 + half);
            u32x2 r = rp[(size_t)(v & 0x1FFFF) * 32 + l32];
            acc1(v, r);
        }
    }
    s.x += __shfl_xor(s.x, 32);
    s.y += __shfl_xor(s.y, 32);
    s.z += __shfl_xor(s.z, 32);
    s.w += __shfl_xor(s.w, 32);
    if (half == 0) {
        u32x2 ov;
        ov.x = h22bits(__floats2half2_rn(s.x, s.y));
        ov.y = h22bits(__floats2half2_rn(s.z, s.w));
        ((u32x2*)rep_out)[(size_t)node * 32 + l32] = ov;
    }
}

// ---------- final user rows: 0.25*(emb + r1 + r2 + r3), fp16 out ----------
__global__ __launch_bounds__(256) void gather_users(const int* __restrict__ users,
                                                    const float* __restrict__ emb,
                                                    const __half* __restrict__ r1,
                                                    const __half* __restrict__ r2,
                                                    const __half* __restrict__ r3,
                                                    _Float16* __restrict__ ur, int nu) {
    int idx = blockIdx.x * 256 + threadIdx.x;
    int u = idx >> 5;
    int q = idx & 31;
    if (u >= nu) return;
    size_t row = (size_t)users[u];
    f4 e = *(const f4*)(emb + row * EMBED + q * 4);
    size_t p = row * 32 + q;
    u32x2 a = ((const u32x2*)r1)[p];
    u32x2 b = ((const u32x2*)r2)[p];
    u32x2 c = ((const u32x2*)r3)[p];
    float2 a0 = __half22float2(bits2h2(a.x)), a1 = __half22float2(bits2h2(a.y));
    float2 b0 = __half22float2(bits2h2(b.x)), b1 = __half22float2(bits2h2(b.y));
    float2 c0 = __half22float2(bits2h2(c.x)), c1 = __half22float2(bits2h2(c.y));
    float v0 = (e.x + a0.x + b0.x + c0.x) * 0.25f;
    float v1 = (e.y + a0.y + b0.y + c0.y) * 0.25f;
    float v2 = (e.z + a1.x + b1.x + c1.x) * 0.25f;
    float v3 = (e.w + a1.y + b1.y + c1.y) * 0.25f;
    u32x2 o;
    o.x = h22bits(__floats2half2_rn(v0, v1));
    o.y = h22bits(__floats2half2_rn(v2, v3));
    *(u32x2*)(ur + (size_t)u * EMBED + q * 4) = o;
}

// ---------- final item rows: 0.25*(emb + r1 + r2 + r3), fp16 out ----------
__global__ __launch_bounds__(256) void copy_items(const float* __restrict__ emb,
                                                  const __half* __restrict__ r1,
                                                  const __half* __restrict__ r2,
                                                  const __half* __restrict__ r3,
                                                  _Float16* __restrict__ ir, int ni) {
    int idx = blockIdx.x * 256 + threadIdx.x;
    int i = idx >> 5;
    int q = idx & 31;
    if (i >= ni) return;
    size_t row = (size_t)(N_USERS_T + i);
    f4 e = *(const f4*)(emb + row * EMBED + q * 4);
    size_t p = row * 32 + q;
    u32x2 a = ((const u32x2*)r1)[p];
    u32x2 b = ((const u32x2*)r2)[p];
    u32x2 c = ((const u32x2*)r3)[p];
    float2 a0 = __half22float2(bits2h2(a.x)), a1 = __half22float2(bits2h2(a.y));
    float2 b0 = __half22float2(bits2h2(b.x)), b1 = __half22float2(bits2h2(b.y));
    float2 c0 = __half22float2(bits2h2(c.x)), c1 = __half22float2(bits2h2(c.y));
    float v0 = (e.x + a0.x + b0.x + c0.x) * 0.25f;
    float v1 = (e.y + a0.y + b0.y + c0.y) * 0.25f;
    float v2 = (e.z + a1.x + b1.x + c1.x) * 0.25f;
    float v3 = (e.w + a1.y + b1.y + c1.y) * 0.25f;
    u32x2 o;
    o.x = h22bits(__floats2half2_rn(v0, v1));
    o.y = h22bits(__floats2half2_rn(v2, v3));
    *(u32x2*)(ir + (size_t)i * EMBED + q * 4) = o;
}

// ---------- MFMA fp16 GEMM: C[nu x nI] = U[nu x 128] * I[nI x 128]^T -------
__global__ __launch_bounds__(256) void gemm_mfma(const _Float16* __restrict__ U,
                                                 const _Float16* __restrict__ I,
                                                 float* __restrict__ C,
                                                 int nu, int nI) {
    int wave = threadIdx.x >> 6;
    int lane = threadIdx.x & 63;
    int i0 = (blockIdx.x * 4 + wave) * 64;
    int u0 = blockIdx.y * 64;
    if (i0 >= nI) return;
    int l16 = lane & 15;
    int kg  = lane >> 4;
    f4 acc[4][4] = {};
    bool inb[4];
    #pragma unroll
    for (int nt = 0; nt < 4; ++nt) inb[nt] = (i0 + nt * 16 + l16) < nI;
    #pragma unroll
    for (int kk = 0; kk < 4; ++kk) {
        const int ko = kk * 32 + kg * 8;
        h8 a[4], b[4];
        #pragma unroll
        for (int mt = 0; mt < 4; ++mt)
            a[mt] = *(const h8*)(U + (size_t)(u0 + mt * 16 + l16) * EMBED + ko);
        #pragma unroll
        for (int nt = 0; nt < 4; ++nt) {
            h8 z = {};
            b[nt] = inb[nt] ? *(const h8*)(I + (size_t)(i0 + nt * 16 + l16) * EMBED + ko) : z;
        }
        #pragma unroll
        for (int mt = 0; mt < 4; ++mt)
            #pragma unroll
            for (int nt = 0; nt < 4; ++nt)
                acc[mt][nt] = __builtin_amdgcn_mfma_f32_16x16x32_f16(a[mt], b[nt], acc[mt][nt], 0, 0, 0);
    }
    #pragma unroll
    for (int mt = 0; mt < 4; ++mt) {
        #pragma unroll
        for (int r = 0; r < 4; ++r) {
            int row = u0 + mt * 16 + kg * 4 + r;
            if (row >= nu) continue;
            float* Cr = C + (size_t)row * nI;
            #pragma unroll
            for (int nt = 0; nt < 4; ++nt) {
                int col = i0 + nt * 16 + l16;
                if (col < nI)
                    __builtin_nontemporal_store(acc[mt][nt][r], Cr + col);
            }
        }
    }
}

extern "C" void kernel_launch(void* const* d_in, const int* in_sizes, int n_in,
                              void* d_out, int out_size, void* d_ws, size_t ws_size,
                              hipStream_t stream) {
    const float* emb   = (const float*)d_in[0];
    const float* ew    = (const float*)d_in[1];
    const int*   esrc  = (const int*)d_in[2];
    const int*   edst  = (const int*)d_in[3];
    const int*   users = (const int*)d_in[4];
    const int n_edges = in_sizes[1];
    const int n_nodes = in_sizes[0] / EMBED;
    const int nu      = in_sizes[4];

    // ---- workspace layout (~27 MB) ----
    char* ws = (char*)d_ws;
    int*      off_end = (int*)ws;                           // 400128 B
    int*      blkhist = (int*)(ws + 400128);                // 400512 B
    int*      cursors = (int*)(ws + 800640);                // 400512 B
    int*      total   = (int*)(ws + 1201152);               // 1664 B
    int*      bbase   = (int*)(ws + 1202816);               // 1664 B
    unsigned* epc     = (unsigned*)(ws + 1204480);          // 12.8 MB
    _Float16* ur      = (_Float16*)(ws + 1204480 + 12800000);           // 256 KB
    _Float16* ir      = (_Float16*)(ws + 1204480 + 12800000 + 262144);  // 12.8 MB

    // ---- d_out doubles as scratch until the final GEMM overwrites it ----
    __half* emb_h   = (__half*)d_out;                       // 25.6 MB
    __half* rep1_h  = emb_h + (size_t)12800000;             // 25.6 MB
    __half* rep2_h  = emb_h + (size_t)2 * 12800000;         // 25.6 MB
    __half* rep3_h  = emb_h + (size_t)3 * 12800000;         // 25.6 MB
    int2*   part_ep = (int2*)(emb_h + (size_t)4 * 12800000);// 25.6 MB (byte 102.4M)
    float*  out     = (float*)d_out;

    const int epb = (n_edges + NBLK - 1) / NBLK;

    // 1) two-level CSR build (compressed edge payload)
    part_hist   <<<NBLK, 256, 0, stream>>>(edst, blkhist, n_edges, epb);
    part_cursors<<<NB,   256, 0, stream>>>(blkhist, cursors, total);
    bucket_base_scan<<<1, 64, 0, stream>>>(total, bbase);
    part_scatter<<<NBLK, 256, 0, stream>>>(esrc, edst, ew, cursors, bbase,
                                           part_ep, n_edges, epb);
    bucket_csr  <<<NB,   512, 0, stream>>>(part_ep, bbase, off_end, epc, n_nodes);

    // 2) fp16 copy of embedding for layer-1 gathers
    int n4 = n_nodes * EMBED / 4;
    f2h_kernel<<<(n4 + 255) / 256, 256, 0, stream>>>(emb, emb_h, n4);

    // 3) three propagation layers (fp16 gather, fp32 math, fp16 rep out)
    const int lgrid = (n_nodes + 3) / 4;
    layer_kernel<<<lgrid, 256, 0, stream>>>(emb_h,  rep1_h, off_end, epc, n_nodes);
    layer_kernel<<<lgrid, 256, 0, stream>>>(rep1_h, rep2_h, off_end, epc, n_nodes);
    layer_kernel<<<lgrid, 256, 0, stream>>>(rep2_h, rep3_h, off_end, epc, n_nodes);

    // 4) final rows: 0.25*(emb + r1 + r2 + r3) -> fp16 ur / ir
    gather_users<<<(nu * 32 + 255) / 256, 256, 0, stream>>>(users, emb, rep1_h, rep2_h, rep3_h, ur, nu);
    copy_items<<<(N_ITEMS * 32 + 255) / 256, 256, 0, stream>>>(emb, rep1_h, rep2_h, rep3_h, ir, N_ITEMS);

    // 5) scores = ur @ ir^T via fp16 MFMA (fp32 accumulate)
    dim3 ggrid((N_ITEMS + 255) / 256, (nu + 63) / 64);
    gemm_mfma<<<ggrid, 256, 0, stream>>>(ur, ir, out, nu, N_ITEMS);
}

// Round 11
// 500.006 us; speedup vs baseline: 1.0760x; 1.0025x over previous
//
#include <hip/hip_runtime.h>
#include <hip/hip_bf16.h>
#include <hip/hip_fp16.h>

typedef float f4 __attribute__((ext_vector_type(4)));
typedef unsigned int u32x2 __attribute__((ext_vector_type(2)));
typedef unsigned int u32x4 __attribute__((ext_vector_type(4)));
typedef _Float16 h8 __attribute__((ext_vector_type(8)));

__device__ __forceinline__ __half2 bits2h2(unsigned u) {
    union { unsigned u; __half2 h; } c; c.u = u; return c.h;
}
__device__ __forceinline__ unsigned h22bits(__half2 h) {
    union { unsigned u; __half2 h; } c; c.h = h; return c.u;
}

#define N_NODES   100000
#define EMBED     128
#define N_USERS_T 50000
#define N_ITEMS   50000

#define BSH   8                 // bucket = dst >> 8
#define NB    391               // ceil(100000 / 256)
#define NBLK  256               // partition blocks

// ---------- K1: per-block bucket histogram ----------
__global__ __launch_bounds__(256) void part_hist(const int* __restrict__ dst,
                                                 int* __restrict__ blkhist,
                                                 int n, int epb) {
    __shared__ int h[NB];
    for (int j = threadIdx.x; j < NB; j += 256) h[j] = 0;
    __syncthreads();
    int b = blockIdx.x, s = b * epb, e = min(n, s + epb);
    for (int i = s + (int)threadIdx.x; i < e; i += 256)
        atomicAdd(&h[dst[i] >> BSH], 1);
    __syncthreads();
    for (int j = threadIdx.x; j < NB; j += 256) blkhist[b * NB + j] = h[j];
}

// ---------- K2a: per-bucket exclusive scan across blocks ----------
__global__ __launch_bounds__(256) void part_cursors(const int* __restrict__ blkhist,
                                                    int* __restrict__ cursors,
                                                    int* __restrict__ total) {
    int bu = blockIdx.x, t = threadIdx.x;
    int v = blkhist[t * NB + bu];
    int lane = t & 63, wid = t >> 6;
    int x = v;
    #pragma unroll
    for (int off = 1; off < 64; off <<= 1) {
        int y = __shfl_up(x, off, 64);
        if (lane >= off) x += y;
    }
    __shared__ int ws4[4];
    if (lane == 63) ws4[wid] = x;
    __syncthreads();
    int add = 0;
    for (int j = 0; j < wid; ++j) add += ws4[j];
    cursors[t * NB + bu] = add + x - v;      // exclusive over blocks
    if (t == 255) total[bu] = add + x;       // bucket size
}

// ---------- K2b: bucket base (serial tiny scan) ----------
__global__ void bucket_base_scan(const int* __restrict__ total,
                                 int* __restrict__ base) {
    if (threadIdx.x == 0) {
        int s = 0;
        for (int j = 0; j < NB; ++j) { base[j] = s; s += total[j]; }
        base[NB] = s;
    }
}

// ---------- K3: partition into buckets (block-private slices) ----------
// part entry: .x = src | (dst_low8 << 17), .y = w bits
__global__ __launch_bounds__(256) void part_scatter(const int* __restrict__ src,
                                                    const int* __restrict__ dst,
                                                    const float* __restrict__ w,
                                                    const int* __restrict__ cursors,
                                                    const int* __restrict__ base,
                                                    int2* __restrict__ part,
                                                    int n, int epb) {
    __shared__ int cur[NB];
    int b = blockIdx.x;
    for (int j = threadIdx.x; j < NB; j += 256)
        cur[j] = base[j] + cursors[b * NB + j];
    __syncthreads();
    int s = b * epb, e = min(n, s + epb);
    for (int i = s + (int)threadIdx.x; i < e; i += 256) {
        int d = dst[i];
        int bu = d >> BSH;
        int p = atomicAdd(&cur[bu], 1);
        int2 pe;
        pe.x = src[i] | ((d & 255) << 17);
        pe.y = __float_as_int(w[i]);
        part[p] = pe;
    }
}

// ---------- K4: per-bucket fine CSR; emits compressed edge u32 -------------
// edge u32 = src (17b) | wq (15b fixed-point w*32768)
__global__ __launch_bounds__(512) void bucket_csr(const int2* __restrict__ part,
                                                  const int* __restrict__ base,
                                                  int* __restrict__ off_end,
                                                  unsigned* __restrict__ ep,
                                                  int n_nodes) {
    __shared__ int cnt[256], cur2[256], ws4[4];
    int bu = blockIdx.x, t = threadIdx.x;
    int b0 = base[bu], b1 = base[bu + 1];
    if (t < 256) cnt[t] = 0;
    __syncthreads();
    for (int i = b0 + t; i < b1; i += 512)
        atomicAdd(&cnt[(part[i].x >> 17) & 255], 1);
    __syncthreads();
    int lane = t & 63, wid = t >> 6;
    int v = 0, x = 0;
    if (t < 256) {
        v = cnt[t]; x = v;
        #pragma unroll
        for (int off = 1; off < 64; off <<= 1) {
            int y = __shfl_up(x, off, 64);
            if (lane >= off) x += y;
        }
        if (lane == 63) ws4[wid] = x;
    }
    __syncthreads();
    if (t < 256) {
        int add = 0;
        for (int j = 0; j < wid; ++j) add += ws4[j];
        int incl = add + x;
        int node = (bu << BSH) + t;
        if (node < n_nodes) off_end[node] = b0 + incl;
        cur2[t] = b0 + incl - v;             // exclusive start
    }
    __syncthreads();
    for (int i = b0 + t; i < b1; i += 512) {
        int2 pe = part[i];
        int dloc = (pe.x >> 17) & 255;
        int p = atomicAdd(&cur2[dloc], 1);
        float wf = __int_as_float(pe.y);
        int wq = (int)(wf * 32768.f + 0.5f);
        wq = min(max(wq, 0), 32767);
        ep[p] = (unsigned)(pe.x & 0x1FFFF) | ((unsigned)wq << 17);
    }
}

// ---------- fp32 -> fp16 row conversion ----------
__global__ __launch_bounds__(256) void f2h_kernel(const float* __restrict__ in,
                                                  __half* __restrict__ out, int n4) {
    int i = blockIdx.x * 256 + threadIdx.x;
    if (i < n4) {
        f4 v = ((const f4*)in)[i];
        u32x2 o;
        o.x = h22bits(__floats2half2_rn(v.x, v.y));
        o.y = h22bits(__floats2half2_rn(v.z, v.w));
        ((u32x2*)out)[i] = o;
    }
}

// ---------- propagation layer: fp16 gather -> fp16 rep ----------
// Quarter-wave per edge: 16 lanes x 16 B cover the 256-B row; 4 edges per
// batched load instruction, 8 loads in flight = 8 KB/wave outstanding (2x the
// round-10 half-wave version; attacks the MLP limit). Uniform trip count
// np=(m+3)>>2; overrun j>=m reads lanes holding ev=0 -> exact-zero gather.
__global__ __launch_bounds__(256) void layer_kernel(
        const __half* __restrict__ rep_in, __half* __restrict__ rep_out,
        const int* __restrict__ off_end, const unsigned* __restrict__ ep,
        int n_nodes) {
    int node = blockIdx.x * 4 + (threadIdx.x >> 6);
    if (node >= n_nodes) return;
    int lane = threadIdx.x & 63;
    int grp  = lane >> 4;             // 0..3: edge slot within quad
    int l16  = lane & 15;             // 16-B segment of the row
    int beg = (node == 0) ? 0 : off_end[node - 1];
    int end = off_end[node];
    f4 sa = {0.f, 0.f, 0.f, 0.f};     // features l16*8 .. +3
    f4 sb = {0.f, 0.f, 0.f, 0.f};     // features l16*8+4 .. +7
    const u32x4* rp = (const u32x4*)rep_in;   // row = 16 x u32x4

    auto acc1 = [&](unsigned v, u32x4 rv) {
        float wt = (float)(v >> 17) * (1.f / 32768.f);
        float2 f0 = __half22float2(bits2h2(rv.x));
        float2 f1 = __half22float2(bits2h2(rv.y));
        float2 f2 = __half22float2(bits2h2(rv.z));
        float2 f3 = __half22float2(bits2h2(rv.w));
        sa.x = fmaf(wt, f0.x, sa.x);
        sa.y = fmaf(wt, f0.y, sa.y);
        sa.z = fmaf(wt, f1.x, sa.z);
        sa.w = fmaf(wt, f1.y, sa.w);
        sb.x = fmaf(wt, f2.x, sb.x);
        sb.y = fmaf(wt, f2.y, sb.y);
        sb.z = fmaf(wt, f3.x, sb.z);
        sb.w = fmaf(wt, f3.y, sb.w);
    };

    for (int chunk = beg; chunk < end; chunk += 64) {
        int idx = chunk + lane;
        unsigned ev = (idx < end) ? ep[idx] : 0u;
        int m = end - chunk; if (m > 64) m = 64;
        int np = (m + 3) >> 2;            // quad steps: UNIFORM across wave
        int p = 0;
        for (; p + 8 <= np; p += 8) {
            int jb = p * 4 + grp;
            unsigned v0 = __shfl(ev, jb +  0);
            unsigned v1 = __shfl(ev, jb +  4);
            unsigned v2 = __shfl(ev, jb +  8);
            unsigned v3 = __shfl(ev, jb + 12);
            unsigned v4 = __shfl(ev, jb + 16);
            unsigned v5 = __shfl(ev, jb + 20);
            unsigned v6 = __shfl(ev, jb + 24);
            unsigned v7 = __shfl(ev, jb + 28);
            u32x4 r0 = rp[(size_t)(v0 & 0x1FFFF) * 16 + l16];
            u32x4 r1 = rp[(size_t)(v1 & 0x1FFFF) * 16 + l16];
            u32x4 r2 = rp[(size_t)(v2 & 0x1FFFF) * 16 + l16];
            u32x4 r3 = rp[(size_t)(v3 & 0x1FFFF) * 16 + l16];
            u32x4 r4 = rp[(size_t)(v4 & 0x1FFFF) * 16 + l16];
            u32x4 r5 = rp[(size_t)(v5 & 0x1FFFF) * 16 + l16];
            u32x4 r6 = rp[(size_t)(v6 & 0x1FFFF) * 16 + l16];
            u32x4 r7 = rp[(size_t)(v7 & 0x1FFFF) * 16 + l16];
            acc1(v0, r0); acc1(v1, r1); acc1(v2, r2); acc1(v3, r3);
            acc1(v4, r4); acc1(v5, r5); acc1(v6, r6); acc1(v7, r7);
        }
        for (; p < np; ++p) {
            unsigned v = __shfl(ev, p * 4 + grp);
            u32x4 r = rp[(size_t)(v & 0x1FFFF) * 16 + l16];
            acc1(v, r);
        }
    }
    // reduce across the 4 groups (lanes l16, l16+16, l16+32, l16+48)
    sa.x += __shfl_xor(sa.x, 16); sa.y += __shfl_xor(sa.y, 16);
    sa.z += __shfl_xor(sa.z, 16); sa.w += __shfl_xor(sa.w, 16);
    sb.x += __shfl_xor(sb.x, 16); sb.y += __shfl_xor(sb.y, 16);
    sb.z += __shfl_xor(sb.z, 16); sb.w += __shfl_xor(sb.w, 16);
    sa.x += __shfl_xor(sa.x, 32); sa.y += __shfl_xor(sa.y, 32);
    sa.z += __shfl_xor(sa.z, 32); sa.w += __shfl_xor(sa.w, 32);
    sb.x += __shfl_xor(sb.x, 32); sb.y += __shfl_xor(sb.y, 32);
    sb.z += __shfl_xor(sb.z, 32); sb.w += __shfl_xor(sb.w, 32);
    if (grp == 0) {
        u32x4 ov;
        ov.x = h22bits(__floats2half2_rn(sa.x, sa.y));
        ov.y = h22bits(__floats2half2_rn(sa.z, sa.w));
        ov.z = h22bits(__floats2half2_rn(sb.x, sb.y));
        ov.w = h22bits(__floats2half2_rn(sb.z, sb.w));
        ((u32x4*)rep_out)[(size_t)node * 16 + l16] = ov;
    }
}

// ---------- final user rows: 0.25*(emb + r1 + r2 + r3), fp16 out ----------
__global__ __launch_bounds__(256) void gather_users(const int* __restrict__ users,
                                                    const float* __restrict__ emb,
                                                    const __half* __restrict__ r1,
                                                    const __half* __restrict__ r2,
                                                    const __half* __restrict__ r3,
                                                    _Float16* __restrict__ ur, int nu) {
    int idx = blockIdx.x * 256 + threadIdx.x;
    int u = idx >> 5;
    int q = idx & 31;
    if (u >= nu) return;
    size_t row = (size_t)users[u];
    f4 e = *(const f4*)(emb + row * EMBED + q * 4);
    size_t p = row * 32 + q;
    u32x2 a = ((const u32x2*)r1)[p];
    u32x2 b = ((const u32x2*)r2)[p];
    u32x2 c = ((const u32x2*)r3)[p];
    float2 a0 = __half22float2(bits2h2(a.x)), a1 = __half22float2(bits2h2(a.y));
    float2 b0 = __half22float2(bits2h2(b.x)), b1 = __half22float2(bits2h2(b.y));
    float2 c0 = __half22float2(bits2h2(c.x)), c1 = __half22float2(bits2h2(c.y));
    float v0 = (e.x + a0.x + b0.x + c0.x) * 0.25f;
    float v1 = (e.y + a0.y + b0.y + c0.y) * 0.25f;
    float v2 = (e.z + a1.x + b1.x + c1.x) * 0.25f;
    float v3 = (e.w + a1.y + b1.y + c1.y) * 0.25f;
    u32x2 o;
    o.x = h22bits(__floats2half2_rn(v0, v1));
    o.y = h22bits(__floats2half2_rn(v2, v3));
    *(u32x2*)(ur + (size_t)u * EMBED + q * 4) = o;
}

// ---------- final item rows: 0.25*(emb + r1 + r2 + r3), fp16 out ----------
__global__ __launch_bounds__(256) void copy_items(const float* __restrict__ emb,
                                                  const __half* __restrict__ r1,
                                                  const __half* __restrict__ r2,
                                                  const __half* __restrict__ r3,
                                                  _Float16* __restrict__ ir, int ni) {
    int idx = blockIdx.x * 256 + threadIdx.x;
    int i = idx >> 5;
    int q = idx & 31;
    if (i >= ni) return;
    size_t row = (size_t)(N_USERS_T + i);
    f4 e = *(const f4*)(emb + row * EMBED + q * 4);
    size_t p = row * 32 + q;
    u32x2 a = ((const u32x2*)r1)[p];
    u32x2 b = ((const u32x2*)r2)[p];
    u32x2 c = ((const u32x2*)r3)[p];
    float2 a0 = __half22float2(bits2h2(a.x)), a1 = __half22float2(bits2h2(a.y));
    float2 b0 = __half22float2(bits2h2(b.x)), b1 = __half22float2(bits2h2(b.y));
    float2 c0 = __half22float2(bits2h2(c.x)), c1 = __half22float2(bits2h2(c.y));
    float v0 = (e.x + a0.x + b0.x + c0.x) * 0.25f;
    float v1 = (e.y + a0.y + b0.y + c0.y) * 0.25f;
    float v2 = (e.z + a1.x + b1.x + c1.x) * 0.25f;
    float v3 = (e.w + a1.y + b1.y + c1.y) * 0.25f;
    u32x2 o;
    o.x = h22bits(__floats2half2_rn(v0, v1));
    o.y = h22bits(__floats2half2_rn(v2, v3));
    *(u32x2*)(ir + (size_t)i * EMBED + q * 4) = o;
}

// ---------- MFMA fp16 GEMM: C[nu x nI] = U[nu x 128] * I[nI x 128]^T -------
__global__ __launch_bounds__(256) void gemm_mfma(const _Float16* __restrict__ U,
                                                 const _Float16* __restrict__ I,
                                                 float* __restrict__ C,
                                                 int nu, int nI) {
    int wave = threadIdx.x >> 6;
    int lane = threadIdx.x & 63;
    int i0 = (blockIdx.x * 4 + wave) * 64;
    int u0 = blockIdx.y * 64;
    if (i0 >= nI) return;
    int l16 = lane & 15;
    int kg  = lane >> 4;
    f4 acc[4][4] = {};
    bool inb[4];
    #pragma unroll
    for (int nt = 0; nt < 4; ++nt) inb[nt] = (i0 + nt * 16 + l16) < nI;
    #pragma unroll
    for (int kk = 0; kk < 4; ++kk) {
        const int ko = kk * 32 + kg * 8;
        h8 a[4], b[4];
        #pragma unroll
        for (int mt = 0; mt < 4; ++mt)
            a[mt] = *(const h8*)(U + (size_t)(u0 + mt * 16 + l16) * EMBED + ko);
        #pragma unroll
        for (int nt = 0; nt < 4; ++nt) {
            h8 z = {};
            b[nt] = inb[nt] ? *(const h8*)(I + (size_t)(i0 + nt * 16 + l16) * EMBED + ko) : z;
        }
        #pragma unroll
        for (int mt = 0; mt < 4; ++mt)
            #pragma unroll
            for (int nt = 0; nt < 4; ++nt)
                acc[mt][nt] = __builtin_amdgcn_mfma_f32_16x16x32_f16(a[mt], b[nt], acc[mt][nt], 0, 0, 0);
    }
    #pragma unroll
    for (int mt = 0; mt < 4; ++mt) {
        #pragma unroll
        for (int r = 0; r < 4; ++r) {
            int row = u0 + mt * 16 + kg * 4 + r;
            if (row >= nu) continue;
            float* Cr = C + (size_t)row * nI;
            #pragma unroll
            for (int nt = 0; nt < 4; ++nt) {
                int col = i0 + nt * 16 + l16;
                if (col < nI)
                    __builtin_nontemporal_store(acc[mt][nt][r], Cr + col);
            }
        }
    }
}

extern "C" void kernel_launch(void* const* d_in, const int* in_sizes, int n_in,
                              void* d_out, int out_size, void* d_ws, size_t ws_size,
                              hipStream_t stream) {
    const float* emb   = (const float*)d_in[0];
    const float* ew    = (const float*)d_in[1];
    const int*   esrc  = (const int*)d_in[2];
    const int*   edst  = (const int*)d_in[3];
    const int*   users = (const int*)d_in[4];
    const int n_edges = in_sizes[1];
    const int n_nodes = in_sizes[0] / EMBED;
    const int nu      = in_sizes[4];

    // ---- workspace layout (~27 MB) ----
    char* ws = (char*)d_ws;
    int*      off_end = (int*)ws;                           // 400128 B
    int*      blkhist = (int*)(ws + 400128);                // 400512 B
    int*      cursors = (int*)(ws + 800640);                // 400512 B
    int*      total   = (int*)(ws + 1201152);               // 1664 B
    int*      bbase   = (int*)(ws + 1202816);               // 1664 B
    unsigned* epc     = (unsigned*)(ws + 1204480);          // 12.8 MB
    _Float16* ur      = (_Float16*)(ws + 1204480 + 12800000);           // 256 KB
    _Float16* ir      = (_Float16*)(ws + 1204480 + 12800000 + 262144);  // 12.8 MB

    // ---- d_out doubles as scratch until the final GEMM overwrites it ----
    __half* emb_h   = (__half*)d_out;                       // 25.6 MB
    __half* rep1_h  = emb_h + (size_t)12800000;             // 25.6 MB
    __half* rep2_h  = emb_h + (size_t)2 * 12800000;         // 25.6 MB
    __half* rep3_h  = emb_h + (size_t)3 * 12800000;         // 25.6 MB
    int2*   part_ep = (int2*)(emb_h + (size_t)4 * 12800000);// 25.6 MB (byte 102.4M)
    float*  out     = (float*)d_out;

    const int epb = (n_edges + NBLK - 1) / NBLK;

    // 1) two-level CSR build (compressed edge payload)
    part_hist   <<<NBLK, 256, 0, stream>>>(edst, blkhist, n_edges, epb);
    part_cursors<<<NB,   256, 0, stream>>>(blkhist, cursors, total);
    bucket_base_scan<<<1, 64, 0, stream>>>(total, bbase);
    part_scatter<<<NBLK, 256, 0, stream>>>(esrc, edst, ew, cursors, bbase,
                                           part_ep, n_edges, epb);
    bucket_csr  <<<NB,   512, 0, stream>>>(part_ep, bbase, off_end, epc, n_nodes);

    // 2) fp16 copy of embedding for layer-1 gathers
    int n4 = n_nodes * EMBED / 4;
    f2h_kernel<<<(n4 + 255) / 256, 256, 0, stream>>>(emb, emb_h, n4);

    // 3) three propagation layers (fp16 gather, fp32 math, fp16 rep out)
    const int lgrid = (n_nodes + 3) / 4;
    layer_kernel<<<lgrid, 256, 0, stream>>>(emb_h,  rep1_h, off_end, epc, n_nodes);
    layer_kernel<<<lgrid, 256, 0, stream>>>(rep1_h, rep2_h, off_end, epc, n_nodes);
    layer_kernel<<<lgrid, 256, 0, stream>>>(rep2_h, rep3_h, off_end, epc, n_nodes);

    // 4) final rows: 0.25*(emb + r1 + r2 + r3) -> fp16 ur / ir
    gather_users<<<(nu * 32 + 255) / 256, 256, 0, stream>>>(users, emb, rep1_h, rep2_h, rep3_h, ur, nu);
    copy_items<<<(N_ITEMS * 32 + 255) / 256, 256, 0, stream>>>(emb, rep1_h, rep2_h, rep3_h, ir, N_ITEMS);

    // 5) scores = ur @ ir^T via fp16 MFMA (fp32 accumulate)
    dim3 ggrid((N_ITEMS + 255) / 256, (nu + 63) / 64);
    gemm_mfma<<<ggrid, 256, 0, stream>>>(ur, ir, out, nu, N_ITEMS);
}